// Round 4
// baseline (270.181 us; speedup 1.0000x reference)
//
#include <hip/hip_runtime.h>
#include <math.h>

// Problem constants
#define KS    11
#define H     512
#define W     512
#define OH    502
#define OW    502
#define NPLANES 48
#define TOTAL_OUT (NPLANES * OH * OW)   // 12,096,192

// Tiling: 2 wide tiles per row-band. Tile 0: out cols 0..245 (in 0..255)
//         Tile 1: out cols 246..501 (in 246..511)
#define TH      4                 // output rows per block (low -> small LDS -> high occupancy)
#define IROWS   (TH + KS - 1)     // 14 input rows per block
#define LVW     267               // ODD stride: scalar b32 stage-2 reads, exactly 2-way banks (free)
#define NTHREADS 256

__global__ void zero_out_kernel(float* out) { out[0] = 0.0f; }

__global__ __launch_bounds__(NTHREADS) void ssim_kernel(
    const float* __restrict__ x,
    const float* __restrict__ y,
    const float* __restrict__ win,
    float* __restrict__ out)
{
    // 5 vertically-convolved signals: mu_x, mu_y, xx, yy, xy
    // 5*4*267*4 = 21.4 KB -> 7 blocks/CU (28 waves, 87% occupancy ceiling)
    __shared__ float v[5][TH][LVW];
    __shared__ float w1s[KS];
    __shared__ float wsum[NTHREADS / 64];

    const int t     = threadIdx.x;
    const int bx    = blockIdx.x;              // 0 or 1
    const int x0    = bx * 246;                // col base (input & output)
    const int gy0   = blockIdx.y * TH;         // output row base
    const int plane = blockIdx.z;
    const int IWx   = bx ? 266 : 256;          // input cols this tile
    const int TWx   = bx ? 256 : 246;          // output cols this tile

    const float* __restrict__ xp = x + (size_t)plane * (H * W);
    const float* __restrict__ yp = y + (size_t)plane * (H * W);

    // Separable taps: window = outer(g,g) => g[i] = sqrt(win[i][i])
    if (t < KS) w1s[t] = sqrtf(win[t * KS + t]);
    __syncthreads();

    float w[KS];
#pragma unroll
    for (int k = 0; k < KS; k++) w[k] = w1s[k];

    // ---- Stage 1: vertical 11-tap conv, global -> regs -> LDS ----
    // Thread owns a column; scatter each input row into the <=4 output rows it feeds.
    for (int cc = t; cc < IWx; cc += NTHREADS) {
        const int gx = x0 + cc;                // < 512 by construction
        float a0[TH], a1[TH], a2[TH], a3[TH], a4[TH];
#pragma unroll
        for (int rr = 0; rr < TH; rr++) { a0[rr] = 0.f; a1[rr] = 0.f; a2[rr] = 0.f; a3[rr] = 0.f; a4[rr] = 0.f; }

#pragma unroll
        for (int j = 0; j < IROWS; j++) {
            const int gy = gy0 + j;
            float xv = 0.f, yv = 0.f;
            if (gy < H) {                      // uniform branch; zero-fill never reaches valid outputs
                xv = xp[gy * W + gx];
                yv = yp[gy * W + gx];
            }
            const float xx = xv * xv;
            const float yy = yv * yv;
            const float xy = xv * yv;
#pragma unroll
            for (int rr = 0; rr < TH; rr++) {
                if (j - rr >= 0 && j - rr < KS) {   // constant-folds after unroll
                    const float wk = w[j - rr];
                    a0[rr] += wk * xv;
                    a1[rr] += wk * yv;
                    a2[rr] += wk * xx;
                    a3[rr] += wk * yy;
                    a4[rr] += wk * xy;
                }
            }
        }
#pragma unroll
        for (int rr = 0; rr < TH; rr++) {
            v[0][rr][cc] = a0[rr];
            v[1][rr][cc] = a1[rr];
            v[2][rr][cc] = a2[rr];
            v[3][rr][cc] = a3[rr];
            v[4][rr][cc] = a4[rr];
        }
    }
    __syncthreads();

    // ---- Stage 2: horizontal 11-tap conv over a 4-pixel run + SSIM ----
    const int r  = t & 3;            // row within tile
    const int c0 = (t >> 2) << 2;    // run start col: 0..252

    float mu[5][TH];
#pragma unroll
    for (int s = 0; s < 5; s++) {
        float vs[IROWS];
#pragma unroll
        for (int j = 0; j < IROWS; j++) vs[j] = v[s][r][c0 + j];
#pragma unroll
        for (int p = 0; p < TH; p++) {
            float m = 0.f;
#pragma unroll
            for (int k = 0; k < KS; k++) m += w[k] * vs[p + k];
            mu[s][p] = m;
        }
    }

    const float c1 = 1e-4f;   // (0.01)^2
    const float c2 = 9e-4f;   // (0.03)^2
    const int grow = gy0 + r;
    float acc = 0.f;
#pragma unroll
    for (int p = 0; p < TH; p++) {
        if ((c0 + p) < TWx && grow < OH) {
            const float a = mu[0][p], b = mu[1][p];
            const float sxx = mu[2][p] - a * a;
            const float syy = mu[3][p] - b * b;
            const float sxy = mu[4][p] - a * b;
            const float num = (2.f * sxy + c2) * (2.f * a * b + c1);
            const float den = (sxx + syy + c2) * (a * a + b * b + c1);
            acc += num * __builtin_amdgcn_rcpf(den);
        }
    }

    // ---- Reduction: wave shuffle -> cross-wave LDS -> one atomic/block ----
#pragma unroll
    for (int off = 32; off > 0; off >>= 1)
        acc += __shfl_down(acc, off, 64);

    if ((t & 63) == 0) wsum[t >> 6] = acc;
    __syncthreads();
    if (t == 0) {
        float s = 0.f;
#pragma unroll
        for (int i = 0; i < NTHREADS / 64; i++) s += wsum[i];
        atomicAdd(out, s * (1.0f / (float)TOTAL_OUT));
    }
}

extern "C" void kernel_launch(void* const* d_in, const int* in_sizes, int n_in,
                              void* d_out, int out_size, void* d_ws, size_t ws_size,
                              hipStream_t stream)
{
    const float* x   = (const float*)d_in[0];
    const float* y   = (const float*)d_in[1];
    const float* win = (const float*)d_in[2];
    float* out = (float*)d_out;

    zero_out_kernel<<<1, 1, 0, stream>>>(out);

    dim3 grid(2, (OH + TH - 1) / TH, NPLANES);   // (2, 126, 48) = 12096 blocks
    ssim_kernel<<<grid, NTHREADS, 0, stream>>>(x, y, win, out);
}

// Round 5
// 229.314 us; speedup vs baseline: 1.1782x; 1.1782x over previous
//
#include <hip/hip_runtime.h>
#include <math.h>

// Problem constants
#define KS    11
#define H     512
#define W     512
#define OH    502
#define OW    502
#define NPLANES 48
#define TOTAL_OUT (NPLANES * OH * OW)   // 12,096,192

// Tiling: 3 column strips x 63 row-bands.
//   strip out bases {0,178,356}, widths {178,178,146}
//   strip in  bases {0,176,356} (float4-aligned), 192 input cols each
#define TH      8                  // output rows per block
#define IROWS   (TH + KS - 1)      // 18 input rows
#define IW      192                // input cols per strip
#define NF4     48                 // IW/4
#define SIW     192                // staged-tile LDS row stride (words, f4-aligned)
#define LVW     193                // v row stride (odd -> 2-way banks, free)
#define NTHREADS 256
#define YOFF    (IROWS * SIW)      // 3456 words: y tile offset
#define LDSWORDS (5 * TH * LVW + 8) // 7728 words; +8 pad absorbs stage-C tail reads

__global__ void zero_out_kernel(float* out) { out[0] = 0.0f; }

__global__ __launch_bounds__(NTHREADS) void ssim_kernel(
    const float* __restrict__ x,
    const float* __restrict__ y,
    const float* __restrict__ win,
    float* __restrict__ out)
{
    // Union: stage A/B input tiles (2*18*192 = 6912 w) then v[5][8][193] (7720 w)
    __shared__ float lds[LDSWORDS];        // 30.9 KB -> 5 blocks/CU
    __shared__ float w1s[KS];
    __shared__ float wsum[NTHREADS / 64];

    const int t     = threadIdx.x;
    const int bx    = blockIdx.x;               // 0..2
    const int gy0   = blockIdx.y * TH;
    const int plane = blockIdx.z;
    const int out_base = bx * 178;
    const int out_w    = (bx == 2) ? 146 : 178;
    const int in_base  = out_base & ~3;         // 0,176,356
    const int c0off    = out_base - in_base;    // 0,2,0

    const float* __restrict__ xp = x + (size_t)plane * (H * W);
    const float* __restrict__ yp = y + (size_t)plane * (H * W);

    // Separable taps: window = outer(g,g) => g[i] = sqrt(win[i][i])
    if (t < KS) w1s[t] = sqrtf(win[t * (KS + 1)]);

    // ---- Stage A: cooperative float4 staging of x,y tiles (18 x 192 each) ----
    {
        float4 rx[4], ry[4];
        bool act[4];
#pragma unroll
        for (int i = 0; i < 4; i++) {
            const int f = t + NTHREADS * i;          // f4 index in tile
            act[i] = (f < IROWS * NF4);              // 864 total
            const int row = f / NF4;                 // const divisor -> magic mul
            const int c4  = f - row * NF4;
            const int gy  = gy0 + row;
            const int gx  = in_base + 4 * c4;
            rx[i] = make_float4(0.f, 0.f, 0.f, 0.f);
            ry[i] = make_float4(0.f, 0.f, 0.f, 0.f);
            if (act[i] && gy < H && gx < W) {        // zero-fill OOB (feeds only masked outputs)
                rx[i] = *(const float4*)(xp + (size_t)gy * W + gx);
                ry[i] = *(const float4*)(yp + (size_t)gy * W + gx);
            }
        }
        float4* lx = (float4*)lds;
        float4* ly = (float4*)(lds + YOFF);
#pragma unroll
        for (int i = 0; i < 4; i++) {
            const int f = t + NTHREADS * i;
            if (act[i]) { lx[f] = rx[i]; ly[f] = ry[i]; }
        }
    }
    __syncthreads();

    float w[KS];
#pragma unroll
    for (int k = 0; k < KS; k++) w[k] = w1s[k];

    // ---- Stage B: vertical 11-tap conv, thread-per-column from LDS ----
    float a0[TH], a1[TH], a2[TH], a3[TH], a4[TH];
    const bool colActive = (t < IW);
    if (colActive) {
#pragma unroll
        for (int rr = 0; rr < TH; rr++) { a0[rr]=0.f; a1[rr]=0.f; a2[rr]=0.f; a3[rr]=0.f; a4[rr]=0.f; }
#pragma unroll
        for (int j = 0; j < IROWS; j++) {
            const float xv = lds[j * SIW + t];          // consecutive lanes -> conflict-free
            const float yv = lds[YOFF + j * SIW + t];
            const float xx = xv * xv, yy = yv * yv, xy = xv * yv;
#pragma unroll
            for (int rr = 0; rr < TH; rr++) {
                if (j - rr >= 0 && j - rr < KS) {       // constant-folds after unroll
                    const float wk = w[j - rr];
                    a0[rr] += wk * xv;  a1[rr] += wk * yv;
                    a2[rr] += wk * xx;  a3[rr] += wk * yy;  a4[rr] += wk * xy;
                }
            }
        }
    }
    __syncthreads();             // all staged-tile reads done before overwrite
    if (colActive) {
#pragma unroll
        for (int rr = 0; rr < TH; rr++) {
            lds[0 * TH * LVW + rr * LVW + t] = a0[rr];
            lds[1 * TH * LVW + rr * LVW + t] = a1[rr];
            lds[2 * TH * LVW + rr * LVW + t] = a2[rr];
            lds[3 * TH * LVW + rr * LVW + t] = a3[rr];
            lds[4 * TH * LVW + rr * LVW + t] = a4[rr];
        }
    }
    __syncthreads();

    // ---- Stage C: horizontal 11-tap conv over an 8-pixel run + SSIM ----
    const int r  = t & 7;
    const int c0 = (t >> 3) << 3;
    float acc = 0.f;
    if (c0 < out_w) {
        float mu[5][TH];
#pragma unroll
        for (int s = 0; s < 5; s++) {
            const float* __restrict__ vr = &lds[s * TH * LVW + r * LVW + c0off + c0];
            float vs[IROWS];
#pragma unroll
            for (int j = 0; j < IROWS; j++) vs[j] = vr[j];
#pragma unroll
            for (int p = 0; p < TH; p++) {
                float m = 0.f;
#pragma unroll
                for (int k = 0; k < KS; k++) m += w[k] * vs[p + k];
                mu[s][p] = m;
            }
        }
        const float c1 = 1e-4f;   // (0.01)^2
        const float c2 = 9e-4f;   // (0.03)^2
        const int grow = gy0 + r;
#pragma unroll
        for (int p = 0; p < TH; p++) {
            if ((c0 + p) < out_w && grow < OH) {
                const float a = mu[0][p], b = mu[1][p];
                const float sxx = mu[2][p] - a * a;
                const float syy = mu[3][p] - b * b;
                const float sxy = mu[4][p] - a * b;
                const float num = (2.f * sxy + c2) * (2.f * a * b + c1);
                const float den = (sxx + syy + c2) * (a * a + b * b + c1);
                acc += num * __builtin_amdgcn_rcpf(den);
            }
        }
    }

    // ---- Reduction: wave shuffle -> cross-wave LDS -> one atomic/block ----
#pragma unroll
    for (int off = 32; off > 0; off >>= 1)
        acc += __shfl_down(acc, off, 64);

    if ((t & 63) == 0) wsum[t >> 6] = acc;
    __syncthreads();
    if (t == 0) {
        float s = 0.f;
#pragma unroll
        for (int i = 0; i < NTHREADS / 64; i++) s += wsum[i];
        atomicAdd(out, s * (1.0f / (float)TOTAL_OUT));
    }
}

extern "C" void kernel_launch(void* const* d_in, const int* in_sizes, int n_in,
                              void* d_out, int out_size, void* d_ws, size_t ws_size,
                              hipStream_t stream)
{
    const float* x   = (const float*)d_in[0];
    const float* y   = (const float*)d_in[1];
    const float* win = (const float*)d_in[2];
    float* out = (float*)d_out;

    zero_out_kernel<<<1, 1, 0, stream>>>(out);

    dim3 grid(3, (OH + TH - 1) / TH, NPLANES);   // (3, 63, 48) = 9072 blocks
    ssim_kernel<<<grid, NTHREADS, 0, stream>>>(x, y, win, out);
}

// Round 6
// 208.277 us; speedup vs baseline: 1.2972x; 1.1010x over previous
//
#include <hip/hip_runtime.h>
#include <math.h>

// Problem constants
#define KS 11
#define H 512
#define W 512
#define OH 502
#define OW 502
#define NPLANES 48
#define TOTAL_OUT (NPLANES * OH * OW)   // 12,096,192

// Structure: full-row blocks. Thread t owns input cols (2t, 2t+1).
// Vertical 11-tap FIR rolls down the image in a 16-deep register ring
// (16 = power of 2 >= 11 so ring slots are compile-time constants after
// unrolling; batch=4 rows, phase advances 4 mod 16 -> 4 unrolled sub-batches).
// Each batch: 4 v-rows -> LDS -> horizontal 11-tap runs-of-4 + SSIM.
#define BAND 32            // output rows per block (band)
#define NBANDS 16          // 16*32 = 512 >= 502 (tail masked)
#define VS 515             // v-row stride in words; odd -> 2-way banks (free); reads reach col 513
#define NTHREADS 256

__global__ void zero_out_kernel(float* out) { out[0] = 0.0f; }

__global__ __launch_bounds__(NTHREADS) void ssim_kernel(
    const float* __restrict__ x,
    const float* __restrict__ y,
    const float* __restrict__ win,
    float* __restrict__ out)
{
    __shared__ float v[5][4][VS];          // 41.2 KB -> 3 blocks/CU
    __shared__ float w1s[KS];
    __shared__ float wsum[NTHREADS / 64];

    const int t     = threadIdx.x;
    const int band  = blockIdx.x;          // 0..15
    const int plane = blockIdx.y;          // 0..47
    const int j0    = band * BAND;

    // float2 view: row gy, col pair t -> cols (2t, 2t+1)
    const float2* __restrict__ xp2 = (const float2*)(x + (size_t)plane * H * W);
    const float2* __restrict__ yp2 = (const float2*)(y + (size_t)plane * H * W);

    // Separable taps: window = outer(g,g) => g[i] = sqrt(win[i][i])
    if (t < KS) w1s[t] = sqrtf(win[t * (KS + 1)]);

    float2 rx[16], ry[16];                 // input-row ring (cols 2t, 2t+1)
    const float2 z2 = make_float2(0.f, 0.f);

    // ---- Warm-up: fill ring with rows 0..9 of this band ----
#pragma unroll
    for (int lj = 0; lj < 10; ++lj) {
        const int gy = j0 + lj;
        const bool ok = (gy < H);
        rx[lj] = ok ? xp2[gy * 256 + t] : z2;
        ry[lj] = ok ? yp2[gy * 256 + t] : z2;
    }
    __syncthreads();                       // w1s visible

    float w[KS];
#pragma unroll
    for (int k = 0; k < KS; ++k) w[k] = w1s[k];

    // Horizontal mapping: runs of 4. Thread -> (row hr, run q); two runs per thread.
    const int hr   = t & 3;
    const int q    = t >> 2;               // 0..63
    const int c0a  = q << 2;               // 0..252  (all cols valid, no col mask)
    const int c0b  = c0a + 256;            // 256..508 (mask cols >= 502)
    const int c0bc = (c0b > 500) ? 500 : c0b;  // clamp so LDS reads stay in-bounds

    const float c1 = 1e-4f;   // (0.01)^2
    const float c2 = 9e-4f;   // (0.03)^2
    float acc = 0.f;

    // Horizontal run: 5 signals x 14 LDS reads, 4 px of 11-tap conv + SSIM
    auto hrun = [&](int cAddr, int cLog, bool colmask) -> float {
        float mu[5][4];
#pragma unroll
        for (int s = 0; s < 5; ++s) {
            const float* __restrict__ vr = &v[s][hr][cAddr];
            float vs[14];
#pragma unroll
            for (int j = 0; j < 14; ++j) vs[j] = vr[j];
#pragma unroll
            for (int p = 0; p < 4; ++p) {
                float m = 0.f;
#pragma unroll
                for (int k = 0; k < KS; ++k) m = fmaf(w[k], vs[p + k], m);
                mu[s][p] = m;
            }
        }
        float a = 0.f;
#pragma unroll
        for (int p = 0; p < 4; ++p) {
            if (!colmask || (cLog + p) < OW) {
                const float ma = mu[0][p], mb = mu[1][p];
                const float sxx = mu[2][p] - ma * ma;
                const float syy = mu[3][p] - mb * mb;
                const float sxy = mu[4][p] - ma * mb;
                const float num = (2.f * sxy + c2) * (2.f * ma * mb + c1);
                const float den = (sxx + syy + c2) * (ma * ma + mb * mb + c1);
                a += num * __builtin_amdgcn_rcpf(den);
            }
        }
        return a;
    };

    // ---- Main: 8 batches of 4 rows. bp rolled (slots are bp-independent). ----
#pragma unroll 1
    for (int bp = 0; bp < 2; ++bp) {
#pragma unroll
        for (int sub = 0; sub < 4; ++sub) {
            // Vertical: load 4 new rows, emit 4 v-rows into LDS
#pragma unroll
            for (int i = 0; i < 4; ++i) {
                const int ljc  = 10 + 4 * sub + i;     // slot-relevant local row
                const int gy   = j0 + 16 * bp + ljc;
                const int slot = ljc & 15;             // compile-time
                const bool ok  = (gy < H);
                rx[slot] = ok ? xp2[gy * 256 + t] : z2;
                ry[slot] = ok ? yp2[gy * 256 + t] : z2;

                float a0=0.f,a1=0.f,a2=0.f,a3=0.f,a4=0.f;   // col 2t
                float b0=0.f,b1=0.f,b2=0.f,b3=0.f,b4=0.f;   // col 2t+1
#pragma unroll
                for (int k = 0; k < KS; ++k) {
                    const int s2 = (4 * sub + i + k) & 15;  // compile-time
                    const float wk = w[k];
                    {
                        const float xv = rx[s2].x, yv = ry[s2].x;
                        const float t1 = wk * xv, t2 = wk * yv;
                        a0 += t1; a1 += t2;
                        a2 = fmaf(t1, xv, a2); a3 = fmaf(t2, yv, a3); a4 = fmaf(t1, yv, a4);
                    }
                    {
                        const float xv = rx[s2].y, yv = ry[s2].y;
                        const float t1 = wk * xv, t2 = wk * yv;
                        b0 += t1; b1 += t2;
                        b2 = fmaf(t1, xv, b2); b3 = fmaf(t2, yv, b3); b4 = fmaf(t1, yv, b4);
                    }
                }
                const int ca = 2 * t, cb = 2 * t + 1;
                v[0][i][ca] = a0; v[0][i][cb] = b0;
                v[1][i][ca] = a1; v[1][i][cb] = b1;
                v[2][i][ca] = a2; v[2][i][cb] = b2;
                v[3][i][ca] = a3; v[3][i][cb] = b3;
                v[4][i][ca] = a4; v[4][i][cb] = b4;
            }
            __syncthreads();

            // Horizontal + SSIM for out rows j0 + 16bp + 4sub + hr
            const int orow = j0 + 16 * bp + 4 * sub + hr;
            if (orow < OH) {
                acc += hrun(c0a,  c0a, false);
                acc += hrun(c0bc, c0b, true);
            }
            __syncthreads();   // v-buffer consumed before next batch overwrites
        }
    }

    // ---- Reduction: wave shuffle -> cross-wave LDS -> one atomic/block ----
#pragma unroll
    for (int off = 32; off > 0; off >>= 1)
        acc += __shfl_down(acc, off, 64);

    if ((t & 63) == 0) wsum[t >> 6] = acc;
    __syncthreads();
    if (t == 0) {
        float s = 0.f;
#pragma unroll
        for (int i = 0; i < NTHREADS / 64; i++) s += wsum[i];
        atomicAdd(out, s * (1.0f / (float)TOTAL_OUT));
    }
}

extern "C" void kernel_launch(void* const* d_in, const int* in_sizes, int n_in,
                              void* d_out, int out_size, void* d_ws, size_t ws_size,
                              hipStream_t stream)
{
    const float* x   = (const float*)d_in[0];
    const float* y   = (const float*)d_in[1];
    const float* win = (const float*)d_in[2];
    float* out = (float*)d_out;

    zero_out_kernel<<<1, 1, 0, stream>>>(out);

    dim3 grid(NBANDS, NPLANES);   // (16, 48) = 768 blocks = 3.0 blocks/CU
    ssim_kernel<<<grid, NTHREADS, 0, stream>>>(x, y, win, out);
}